// Round 4
// baseline (561.098 us; speedup 1.0000x reference)
//
#include <hip/hip_runtime.h>
#include <hip/hip_bf16.h>
#include <cstdint>
#include <cstddef>

#define T_TOK 4096
#define HID   1024
#define FFN   3584
#define FFI   (2 * FFN)     // interleaved g/u columns: 7168
#define NEXP  8
#define RTOT  (T_TOK * 2)   // total (token, slot) rows = T * top_k
#define MAXT  72            // max 128-row M-tiles: floor(8192/128)+7=71, +1 slack
#define MAXT2 39            // max 256-row M-tiles: floor(8192/256)+7=39
#define BM 128
#define BN 128
#define BK 32
#define BM2 256
#define BN2 256
#define BK2 32
#define NK2 (HID / BK2)     // 32 K-tiles for gemm1
#define NT1B (FFI / BN2)    // 28 N-tiles for gemm1 (256-wide, interleaved)
#define NT2 (HID / BN)      // 8 N-tiles for gemm2

typedef __attribute__((ext_vector_type(8))) short bvec8;   // 8 x bf16 (4 VGPR) MFMA operand
typedef __attribute__((ext_vector_type(4))) short bvec4;
typedef __attribute__((ext_vector_type(4))) float fvec4;   // MFMA accumulator
typedef unsigned short u16;

__device__ __forceinline__ u16 f2b(float f) {
  __bf16 b = (__bf16)f;                 // RNE convert
  return __builtin_bit_cast(u16, b);
}

// async global->LDS, 16B per lane. LDS dest must be wave-uniform base (HW adds lane*16).
__device__ __forceinline__ void gload16(const u16* g, u16* l) {
  __builtin_amdgcn_global_load_lds((const __attribute__((address_space(1))) void*)g,
                                   (__attribute__((address_space(3))) void*)l, 16, 0, 0);
}

// bijective XCD swizzle (m204): contiguous chunk of work per XCD
__device__ __forceinline__ int xcd_swz(int bid, int nwg) {
  int q = nwg >> 3, r = nwg & 7;
  int xcd = bid & 7, sub = bid >> 3;
  return (xcd < r ? xcd * (q + 1) : r * (q + 1) + (xcd - r) * q) + sub;
}

// ---------------- router: logits (fp32), top-2, combine weights, counts, + x->bf16 ------
__global__ void router_kernel(const float* __restrict__ x, const float* __restrict__ gw,
                              float* __restrict__ logits, int* __restrict__ tk_id,
                              float* __restrict__ tk_w, int* __restrict__ counts,
                              u16* __restrict__ xb, int full) {
  const int lane = threadIdx.x & 63;
  const int wid  = threadIdx.x >> 6;
  const int t = blockIdx.x * 4 + wid;          // one token per wave
  const float4* xr = (const float4*)(x + (size_t)t * HID);
  float acc[NEXP] = {0.f, 0.f, 0.f, 0.f, 0.f, 0.f, 0.f, 0.f};
#pragma unroll
  for (int it = 0; it < 4; ++it) {
    int k4 = it * 64 + lane;                   // float4 index, covers H/4 = 256
    float4 xv = xr[k4];
    if (xb) {                                  // fused bf16 cast of x
      bvec4 o;
      o[0] = (short)f2b(xv.x); o[1] = (short)f2b(xv.y);
      o[2] = (short)f2b(xv.z); o[3] = (short)f2b(xv.w);
      *(bvec4*)(xb + (size_t)t * HID + k4 * 4) = o;
    }
    const float* gp = gw + (size_t)k4 * 4 * NEXP;
    float xs[4] = {xv.x, xv.y, xv.z, xv.w};
#pragma unroll
    for (int kk = 0; kk < 4; ++kk) {
      float4 ga = ((const float4*)(gp + kk * NEXP))[0];
      float4 gb = ((const float4*)(gp + kk * NEXP))[1];
      acc[0] += xs[kk] * ga.x; acc[1] += xs[kk] * ga.y;
      acc[2] += xs[kk] * ga.z; acc[3] += xs[kk] * ga.w;
      acc[4] += xs[kk] * gb.x; acc[5] += xs[kk] * gb.y;
      acc[6] += xs[kk] * gb.z; acc[7] += xs[kk] * gb.w;
    }
  }
#pragma unroll
  for (int off = 32; off > 0; off >>= 1) {
#pragma unroll
    for (int e = 0; e < NEXP; ++e) acc[e] += __shfl_xor(acc[e], off, 64);
  }
  if (lane < NEXP) logits[(size_t)t * NEXP + lane] = acc[lane];
  if (full && lane == 0) {
    int e0 = 0; float l0 = acc[0];
#pragma unroll
    for (int e = 1; e < NEXP; ++e) if (acc[e] > l0) { l0 = acc[e]; e0 = e; }
    int e1 = -1; float l1 = -3.4e38f;
#pragma unroll
    for (int e = 0; e < NEXP; ++e) if (e != e0 && acc[e] > l1) { l1 = acc[e]; e1 = e; }
    float w0 = 1.f / (1.f + expf(l1 - l0));
    float w1 = 1.f - w0;
    tk_id[t * 2 + 0] = e0; tk_id[t * 2 + 1] = e1;
    tk_w[t * 2 + 0] = w0;  tk_w[t * 2 + 1] = w1;
    atomicAdd(&counts[e0], 1); atomicAdd(&counts[e1], 1);
  }
}

// ---------------- scan: offsets, tile maps (single thread; 8 experts, trivial) ----------
__global__ void scan_kernel(const int* __restrict__ counts, int* __restrict__ offsets,
                            int* __restrict__ cursors, int4* __restrict__ tilemap,
                            int4* __restrict__ tilemap256) {
  if (threadIdx.x != 0) return;
  int off = 0, nt = 0, nt2 = 0;
  for (int e = 0; e < NEXP; ++e) {
    offsets[e] = off; cursors[e] = 0;
    int c = counts[e];
    for (int tm = 0; tm * BM < c; ++tm)
      tilemap[nt++] = make_int4(e, off + tm * BM, min(BM, c - tm * BM), 0);
    for (int tm = 0; tm * BM2 < c; ++tm)
      tilemap256[nt2++] = make_int4(e, off + tm * BM2, min(BM2, c - tm * BM2), 0);
    off += c;
  }
  offsets[NEXP] = off;
  for (; nt < MAXT; ++nt) tilemap[nt] = make_int4(-1, 0, 0, 0);
  for (; nt2 < MAXT2 + 1; ++nt2) tilemap256[nt2] = make_int4(-1, 0, 0, 0);
}

// ---------------- scatter: build per-expert sorted row lists ----------------------------
__global__ void scatter_kernel(const int* __restrict__ tk_id, const float* __restrict__ tk_w,
                               const int* __restrict__ offsets, int* __restrict__ cursors,
                               int* __restrict__ rowmap, float* __restrict__ roww) {
  int i = blockIdx.x * 256 + threadIdx.x;      // 0 .. RTOT-1
  int t = i >> 1;
  int e = tk_id[i]; float w = tk_w[i];
  int p = atomicAdd(&cursors[e], 1);
  rowmap[offsets[e] + p] = t; roww[offsets[e] + p] = w;
}

// ---------------- transpose-cast w1/w3 -> interleaved Bi[E][FFI][HID] (LDS-staged) ------
// w1 col c -> Bi row 32*(c>>4)+(c&15); w3 col c -> +16. Coalesced reads AND writes.
__global__ void transpose_cast_dual_kernel(const float* __restrict__ w1,
                                           const float* __restrict__ w3,
                                           u16* __restrict__ bi) {
  __shared__ __attribute__((aligned(16))) u16 tile[64][72];
  const int z = blockIdx.z, e = z >> 1, half = z & 1;
  const float* src = (half ? w3 : w1) + (size_t)e * HID * FFN;   // [HID][FFN]
  u16* dst = bi + (size_t)e * FFI * HID;
  const int c0 = blockIdx.x * 64, r0 = blockIdx.y * 64;
  const int t = threadIdx.x;
  const int rr = t >> 4, cc = (t & 15) * 4;
#pragma unroll
  for (int it = 0; it < 4; ++it) {
    int r = it * 16 + rr;
    float4 v = *(const float4*)(src + (size_t)(r0 + r) * FFN + c0 + cc);
    tile[cc + 0][r] = f2b(v.x);
    tile[cc + 1][r] = f2b(v.y);
    tile[cc + 2][r] = f2b(v.z);
    tile[cc + 3][r] = f2b(v.w);
  }
  __syncthreads();
  const int cl = t >> 2;            // local col 0..63
  const int och = (t & 3) * 16;
  const int orow = (c0 << 1) + ((cl >> 4) << 5) + (cl & 15) + (half << 4);
  u16* dp = dst + (size_t)orow * HID + r0 + och;
  *(bvec8*)(dp + 0) = *(const bvec8*)&tile[cl][och + 0];
  *(bvec8*)(dp + 8) = *(const bvec8*)&tile[cl][och + 8];
}

// ---------------- transpose-cast w2 [E][FFN][HID] -> w2t [E][HID][FFN] (LDS-staged) -----
__global__ void transpose_cast_w2_kernel(const float* __restrict__ w2, u16* __restrict__ w2t) {
  __shared__ __attribute__((aligned(16))) u16 tile[64][72];
  const int e = blockIdx.z;
  const float* src = w2 + (size_t)e * FFN * HID;   // [FFN][HID]
  u16* dst = w2t + (size_t)e * HID * FFN;          // [HID][FFN]
  const int c0 = blockIdx.x * 64, r0 = blockIdx.y * 64;
  const int t = threadIdx.x;
  const int rr = t >> 4, cc = (t & 15) * 4;
#pragma unroll
  for (int it = 0; it < 4; ++it) {
    int r = it * 16 + rr;
    float4 v = *(const float4*)(src + (size_t)(r0 + r) * HID + c0 + cc);
    tile[cc + 0][r] = f2b(v.x);
    tile[cc + 1][r] = f2b(v.y);
    tile[cc + 2][r] = f2b(v.z);
    tile[cc + 3][r] = f2b(v.w);
  }
  __syncthreads();
  const int cl = t >> 2;
  const int och = (t & 3) * 16;
  u16* dp = dst + (size_t)(c0 + cl) * FFN + r0 + och;
  *(bvec8*)(dp + 0) = *(const bvec8*)&tile[cl][och + 0];
  *(bvec8*)(dp + 8) = *(const bvec8*)&tile[cl][och + 8];
}

// ---------------- GEMM1: 256x256 8-phase pipeline (T2+T3+T4+T5), interleaved Bi ---------
// 8 waves (2M x 4N), wave out 128x64. K-tile = 32, dbuf by parity, 2 phases/K-tile.
// Staging: phase0 stages A(t+1) [whole 256x32, 2 gloads/thread], phase1 stages B(t+2).
// Gate: vmcnt(2) once per K-tile (vmcnt(0) only for final tile). Raw s_barrier throughout.
// LDS chunk swizzle: phys_chunk = log_chunk ^ ((row>>1)&3), applied on global src + ds_read.
__launch_bounds__(512, 2)
__global__ void gemm1_kernel(const u16* __restrict__ xb, const u16* __restrict__ bi,
                             const int* __restrict__ rowmap,
                             const int4* __restrict__ tilemap256, u16* __restrict__ hbuf) {
  const int wg = xcd_swz(blockIdx.x, NT1B * MAXT2);
  const int mt = wg % MAXT2;         // M fastest within an XCD chunk -> B-panel L2 reuse
  const int nt = wg / MAXT2;
  int4 ti = tilemap256[mt];
  if (ti.x < 0) return;
  const int e = ti.x, rowbase = ti.y, mvalid = ti.z;
  const int n0 = nt * BN2;

  __shared__ __attribute__((aligned(128))) u16 ldsA[2][BM2 * BK2];  // 2 x 16KB
  __shared__ __attribute__((aligned(128))) u16 ldsB[2][BN2 * BK2];  // 2 x 16KB

  const int tid = threadIdx.x;
  const int lane = tid & 63;
  const int wv = tid >> 6;          // 0..7
  const int wm = wv >> 2;           // 0..1 (M half: rows wm*128..+127)
  const int wn = wv & 3;            // 0..3 (N quarter: cols wn*64..+63)
  const int l15 = lane & 15;

  // --- staging geometry: gload g covers tile rows (wv*2+g)*16 + (lane>>2), chunk lane&3 ---
  const int srow0 = (wv * 2 + 0) * 16 + (lane >> 2);
  const int srow1 = (wv * 2 + 1) * 16 + (lane >> 2);
  const int clog8 = (((lane & 3) ^ ((lane >> 3) & 3)) << 3);   // pre-swizzled src chunk
  const int tokA0 = rowmap[min(rowbase + srow0, RTOT - 1)];
  const int tokA1 = rowmap[min(rowbase + srow1, RTOT - 1)];
  const u16* baseA0 = xb + (size_t)tokA0 * HID + clog8;
  const u16* baseA1 = xb + (size_t)tokA1 * HID + clog8;
  const u16* wb = bi + (size_t)e * FFI * HID;
  const u16* baseB0 = wb + (size_t)(n0 + srow0) * HID + clog8;
  const u16* baseB1 = wb + (size_t)(n0 + srow1) * HID + clog8;
  const int dst0 = (wv * 2 + 0) * 512;   // u16 offset: 16 rows x 32
  const int dst1 = (wv * 2 + 1) * 512;

  // --- fragment read offsets (swizzled) ---
  const int aphys8 = (((lane >> 4) ^ ((l15 >> 1) & 3)) << 3);
  const int aoff = (wm * 128 + l15) * BK2 + aphys8;   // + i*512 for m-frag i
  const int boff = (wn * 64 + l15) * BK2 + aphys8;    // + nf*512

  auto STAGE_A = [&](int t) {
    gload16(baseA0 + t * BK2, &ldsA[t & 1][dst0]);
    gload16(baseA1 + t * BK2, &ldsA[t & 1][dst1]);
  };
  auto STAGE_B = [&](int t) {
    gload16(baseB0 + t * BK2, &ldsB[t & 1][dst0]);
    gload16(baseB1 + t * BK2, &ldsB[t & 1][dst1]);
  };

  // --- prologue: A(0), B(0), B(1); keep B(1) in flight ---
  STAGE_A(0); STAGE_B(0); STAGE_B(1);
  asm volatile("s_waitcnt vmcnt(2)" ::: "memory");
  __builtin_amdgcn_s_barrier();

  fvec4 acc[8][4] = {};
  bvec8 bf[4];

  for (int t = 0; t < NK2; ++t) {
    const u16* As = ldsA[t & 1];
    const u16* Bs = ldsB[t & 1];
    // ---- phase 0: m-frags 0-3, load B-frags, stage A(t+1) ----
    bvec8 af[4];
#pragma unroll
    for (int mf = 0; mf < 4; ++mf) af[mf] = *(const bvec8*)&As[aoff + mf * 512];
#pragma unroll
    for (int nf = 0; nf < 4; ++nf) bf[nf] = *(const bvec8*)&Bs[boff + nf * 512];
    if (t < NK2 - 1) STAGE_A(t + 1);
    __builtin_amdgcn_s_barrier();
    asm volatile("s_waitcnt lgkmcnt(0)" ::: "memory");
    __builtin_amdgcn_sched_barrier(0);
    __builtin_amdgcn_s_setprio(1);
#pragma unroll
    for (int nf = 0; nf < 4; ++nf)
#pragma unroll
      for (int mf = 0; mf < 4; ++mf)
        acc[mf][nf] = __builtin_amdgcn_mfma_f32_16x16x32_bf16(af[mf], bf[nf], acc[mf][nf], 0, 0, 0);
    __builtin_amdgcn_s_setprio(0);
    __builtin_amdgcn_s_barrier();
    // ---- phase 1: m-frags 4-7 (reuse bf), stage B(t+2) ----
#pragma unroll
    for (int mf = 0; mf < 4; ++mf) af[mf] = *(const bvec8*)&As[aoff + (4 + mf) * 512];
    if (t < NK2 - 2) STAGE_B(t + 2);
    __builtin_amdgcn_s_barrier();
    asm volatile("s_waitcnt lgkmcnt(0)" ::: "memory");
    __builtin_amdgcn_sched_barrier(0);
    __builtin_amdgcn_s_setprio(1);
#pragma unroll
    for (int nf = 0; nf < 4; ++nf)
#pragma unroll
      for (int mf = 0; mf < 4; ++mf)
        acc[4 + mf][nf] = __builtin_amdgcn_mfma_f32_16x16x32_bf16(af[mf], bf[nf], acc[4 + mf][nf], 0, 0, 0);
    __builtin_amdgcn_s_setprio(0);
    // gate for tile t+1: need A(t+1)@ph0 and B(t+1)@(t-1,ph1) landed; B(t+2) may stay in flight
    if (t < NK2 - 1) {
      if (t == NK2 - 2) asm volatile("s_waitcnt vmcnt(0)" ::: "memory");
      else              asm volatile("s_waitcnt vmcnt(2)" ::: "memory");
    }
    __builtin_amdgcn_s_barrier();
  }

  // ---- epilogue: pair nf (even=g, odd=u): h = silu(g) * u, bf16 ----
  const int rg4 = (lane >> 4) * 4;
  const int hcolbase = ((n0 + wn * 64) >> 1) + l15;
#pragma unroll
  for (int i = 0; i < 8; ++i) {
#pragma unroll
    for (int j = 0; j < 4; ++j) {
      int ml = wm * 128 + i * 16 + rg4 + j;
      if (ml < mvalid) {
        size_t rowoff = (size_t)(rowbase + ml) * FFN + hcolbase;
#pragma unroll
        for (int np = 0; np < 2; ++np) {
          float g = acc[i][2 * np][j], u = acc[i][2 * np + 1][j];
          float hv = (g / (1.f + expf(-g))) * u;
          hbuf[rowoff + np * 16] = f2b(hv);
        }
      }
    }
  }
}

// ---------------- GEMM2: out[token] += weight * (h @ w2), grouped by expert -------------
__launch_bounds__(256, 3)
__global__ void gemm2_kernel(const u16* __restrict__ hbuf, const u16* __restrict__ w2t,
                             const int* __restrict__ rowmap, const float* __restrict__ roww,
                             const int4* __restrict__ tilemap, float* __restrict__ out) {
  const int wg = xcd_swz(blockIdx.x, NT2 * MAXT);
  const int mt = wg % MAXT;
  const int nt = wg / MAXT;
  int4 ti = tilemap[mt];
  if (ti.x < 0) return;
  const int e = ti.x, rowbase = ti.y, mvalid = ti.z;
  const int n0 = nt * BN;

  __shared__ __attribute__((aligned(128))) u16 As[BM * BK];
  __shared__ __attribute__((aligned(128))) u16 Bs[BN * BK];

  const int tid = threadIdx.x;
  const int lane = tid & 63;
  const int w = tid >> 6;

  const int r16 = lane >> 2;
  const int csrc = ((lane & 3) ^ ((lane >> 3) & 3)) * 8;
  const int rA0 = w * 16 + r16, rA1 = 64 + w * 16 + r16;
  const u16* gA0 = hbuf + (size_t)min(rowbase + rA0, RTOT - 1) * FFN + csrc;
  const u16* gA1 = hbuf + (size_t)min(rowbase + rA1, RTOT - 1) * FFN + csrc;
  const u16* wb2 = w2t + (size_t)e * HID * FFN;
  const u16* gB0 = wb2 + (size_t)(n0 + rA0) * FFN + csrc;
  const u16* gB1 = wb2 + (size_t)(n0 + rA1) * FFN + csrc;

  u16* lA0 = &As[(w * 16) * BK];
  u16* lA1 = &As[(64 + w * 16) * BK];
  u16* lB0 = &Bs[(w * 16) * BK];
  u16* lB1 = &Bs[(64 + w * 16) * BK];

  const int wm = (tid >> 7) & 1, wn = (tid >> 6) & 1;
  const int l15 = lane & 15;
  const int pkg8 = (((lane >> 4) ^ ((lane >> 1) & 3)) << 3);
  const int iA = (wm * 64 + l15) * BK + pkg8;
  const int iB = (wn * 64 + l15) * BK + pkg8;

  fvec4 acc[4][4] = {};

  for (int kt = 0; kt < FFN / BK; ++kt) {
    gload16(gA0, lA0); gload16(gA1, lA1);
    gload16(gB0, lB0); gload16(gB1, lB1);
    gA0 += BK; gA1 += BK; gB0 += BK; gB1 += BK;
    __syncthreads();
    bvec8 a[4];
#pragma unroll
    for (int mi = 0; mi < 4; ++mi)
      a[mi] = *(const bvec8*)&As[iA + mi * 16 * BK];
#pragma unroll
    for (int ni = 0; ni < 4; ++ni) {
      bvec8 b = *(const bvec8*)&Bs[iB + ni * 16 * BK];
#pragma unroll
      for (int mi = 0; mi < 4; ++mi)
        acc[mi][ni] = __builtin_amdgcn_mfma_f32_16x16x32_bf16(a[mi], b, acc[mi][ni], 0, 0, 0);
    }
    __syncthreads();
  }
  // epilogue: weighted atomic combine into out[token]
  const int rg4 = (lane >> 4) * 4;
#pragma unroll
  for (int mi = 0; mi < 4; ++mi) {
#pragma unroll
    for (int j = 0; j < 4; ++j) {
      int ml = wm * 64 + mi * 16 + rg4 + j;
      if (ml < mvalid) {
        int r = rowbase + ml;
        int tk = rowmap[r];
        float wgt = roww[r];
        float* op = out + (size_t)tk * HID + n0 + wn * 64;
#pragma unroll
        for (int ni = 0; ni < 4; ++ni)
          atomicAdd(&op[ni * 16 + l15], acc[mi][ni][j] * wgt);
      }
    }
  }
}

// ---------------- launcher --------------------------------------------------------------
extern "C" void kernel_launch(void* const* d_in, const int* in_sizes, int n_in,
                              void* d_out, int out_size, void* d_ws, size_t ws_size,
                              hipStream_t stream) {
  (void)in_sizes; (void)n_in; (void)out_size;
  const float* x  = (const float*)d_in[0];
  const float* gw = (const float*)d_in[1];
  const float* w1 = (const float*)d_in[2];
  const float* w2 = (const float*)d_in[3];   // NOTE: dict order is w1, w2, w3
  const float* w3 = (const float*)d_in[4];
  float* out = (float*)d_out;
  float* logits = out + (size_t)T_TOK * HID;

  size_t off = 0;
  auto take = [&](size_t b) { size_t o = off; off += (b + 255) & ~(size_t)255; return o; };
  size_t o_xb   = take((size_t)T_TOK * HID * 2);           // x bf16
  size_t o_wt   = take((size_t)NEXP * FFI * HID * 2);      // Bi (interleaved w1/w3); w2t reuses
  size_t o_hb   = take((size_t)RTOT * FFN * 2);            // h bf16
  size_t o_rmap = take((size_t)RTOT * 4);
  size_t o_rw   = take((size_t)RTOT * 4);
  size_t o_tid  = take((size_t)RTOT * 4);
  size_t o_tw   = take((size_t)RTOT * 4);
  size_t o_cnt  = take(4 * NEXP);
  size_t o_ofs  = take(4 * (NEXP + 1));
  size_t o_cur  = take(4 * NEXP);
  size_t o_tmap = take(MAXT * 16);
  size_t o_tmap2= take((MAXT2 + 1) * 16);
  size_t total = off;

  hipMemsetAsync(d_out, 0, (size_t)T_TOK * HID * sizeof(float), stream);
  if (ws_size < total) {
    router_kernel<<<T_TOK / 4, 256, 0, stream>>>(x, gw, logits, nullptr, nullptr, nullptr,
                                                 nullptr, 0);
    return;
  }

  char* w = (char*)d_ws;
  u16* xb   = (u16*)(w + o_xb);
  u16* bi   = (u16*)(w + o_wt);
  u16* w2t  = bi;                                   // reused after gemm1 completes
  u16* hb   = (u16*)(w + o_hb);
  int*   rmap = (int*)(w + o_rmap);
  float* rw   = (float*)(w + o_rw);
  int*   tkid = (int*)(w + o_tid);
  float* tkw  = (float*)(w + o_tw);
  int*   cnt  = (int*)(w + o_cnt);
  int*   ofs  = (int*)(w + o_ofs);
  int*   cur  = (int*)(w + o_cur);
  int4*  tmap = (int4*)(w + o_tmap);
  int4*  tmap2= (int4*)(w + o_tmap2);

  hipMemsetAsync(cnt, 0, 4 * NEXP, stream);
  router_kernel<<<T_TOK / 4, 256, 0, stream>>>(x, gw, logits, tkid, tkw, cnt, xb, 1);
  scan_kernel<<<1, 64, 0, stream>>>(cnt, ofs, cur, tmap, tmap2);
  scatter_kernel<<<RTOT / 256, 256, 0, stream>>>(tkid, tkw, ofs, cur, rmap, rw);
  transpose_cast_dual_kernel<<<dim3(FFN / 64, HID / 64, 2 * NEXP), 256, 0, stream>>>(w1, w3, bi);
  gemm1_kernel<<<NT1B * MAXT2, 512, 0, stream>>>(xb, bi, rmap, tmap2, hb);
  transpose_cast_w2_kernel<<<dim3(HID / 64, FFN / 64, NEXP), 256, 0, stream>>>(w2, w2t);
  gemm2_kernel<<<NT2 * MAXT, 256, 0, stream>>>(hb, w2t, rmap, rw, tmap, out);
}

// Round 5
// 514.277 us; speedup vs baseline: 1.0910x; 1.0910x over previous
//
#include <hip/hip_runtime.h>
#include <hip/hip_bf16.h>
#include <cstdint>
#include <cstddef>

#define T_TOK 4096
#define HID   1024
#define FFN   3584
#define FFI   (2 * FFN)     // interleaved g/u columns: 7168
#define NEXP  8
#define RTOT  (T_TOK * 2)   // total (token, slot) rows = T * top_k
#define MAXT  72            // max 128-row M-tiles: floor(8192/128)+7=71, +1 slack
#define MAXT64 136          // max 64-row M-tiles: 8192/64 + 8 = 136
#define BM 128
#define BN 128
#define BK 64               // K-tile (halves barrier count vs 32)
#define NT1 (FFI / BN)      // 56 N-tiles for gemm1 (interleaved)
#define NT2 (HID / 128)     // 8 N-tiles for gemm2 (BN2=128)

typedef __attribute__((ext_vector_type(8))) short bvec8;   // 8 x bf16 (4 VGPR) MFMA operand
typedef __attribute__((ext_vector_type(4))) short bvec4;
typedef __attribute__((ext_vector_type(4))) float fvec4;   // MFMA accumulator
typedef unsigned short u16;

__device__ __forceinline__ u16 f2b(float f) {
  __bf16 b = (__bf16)f;                 // RNE convert
  return __builtin_bit_cast(u16, b);
}

// async global->LDS, 16B per lane. LDS dest must be wave-uniform base (HW adds lane*16).
__device__ __forceinline__ void gload16(const u16* g, u16* l) {
  __builtin_amdgcn_global_load_lds((const __attribute__((address_space(1))) void*)g,
                                   (__attribute__((address_space(3))) void*)l, 16, 0, 0);
}

// bijective XCD swizzle (m204): contiguous chunk of work per XCD
__device__ __forceinline__ int xcd_swz(int bid, int nwg) {
  int q = nwg >> 3, r = nwg & 7;
  int xcd = bid & 7, sub = bid >> 3;
  return (xcd < r ? xcd * (q + 1) : r * (q + 1) + (xcd - r) * q) + sub;
}

// ---------------- router: logits (fp32), top-2, combine weights, counts, + x->bf16 ------
__global__ void router_kernel(const float* __restrict__ x, const float* __restrict__ gw,
                              float* __restrict__ logits, int* __restrict__ tk_id,
                              float* __restrict__ tk_w, int* __restrict__ counts,
                              u16* __restrict__ xb, int full) {
  const int lane = threadIdx.x & 63;
  const int wid  = threadIdx.x >> 6;
  const int t = blockIdx.x * 4 + wid;          // one token per wave
  const float4* xr = (const float4*)(x + (size_t)t * HID);
  float acc[NEXP] = {0.f, 0.f, 0.f, 0.f, 0.f, 0.f, 0.f, 0.f};
#pragma unroll
  for (int it = 0; it < 4; ++it) {
    int k4 = it * 64 + lane;                   // float4 index, covers H/4 = 256
    float4 xv = xr[k4];
    if (xb) {                                  // fused bf16 cast of x
      bvec4 o;
      o[0] = (short)f2b(xv.x); o[1] = (short)f2b(xv.y);
      o[2] = (short)f2b(xv.z); o[3] = (short)f2b(xv.w);
      *(bvec4*)(xb + (size_t)t * HID + k4 * 4) = o;
    }
    const float* gp = gw + (size_t)k4 * 4 * NEXP;
    float xs[4] = {xv.x, xv.y, xv.z, xv.w};
#pragma unroll
    for (int kk = 0; kk < 4; ++kk) {
      float4 ga = ((const float4*)(gp + kk * NEXP))[0];
      float4 gb = ((const float4*)(gp + kk * NEXP))[1];
      acc[0] += xs[kk] * ga.x; acc[1] += xs[kk] * ga.y;
      acc[2] += xs[kk] * ga.z; acc[3] += xs[kk] * ga.w;
      acc[4] += xs[kk] * gb.x; acc[5] += xs[kk] * gb.y;
      acc[6] += xs[kk] * gb.z; acc[7] += xs[kk] * gb.w;
    }
  }
#pragma unroll
  for (int off = 32; off > 0; off >>= 1) {
#pragma unroll
    for (int e = 0; e < NEXP; ++e) acc[e] += __shfl_xor(acc[e], off, 64);
  }
  if (lane < NEXP) logits[(size_t)t * NEXP + lane] = acc[lane];
  if (full && lane == 0) {
    int e0 = 0; float l0 = acc[0];
#pragma unroll
    for (int e = 1; e < NEXP; ++e) if (acc[e] > l0) { l0 = acc[e]; e0 = e; }
    int e1 = -1; float l1 = -3.4e38f;
#pragma unroll
    for (int e = 0; e < NEXP; ++e) if (e != e0 && acc[e] > l1) { l1 = acc[e]; e1 = e; }
    float w0 = 1.f / (1.f + expf(l1 - l0));
    float w1 = 1.f - w0;
    tk_id[t * 2 + 0] = e0; tk_id[t * 2 + 1] = e1;
    tk_w[t * 2 + 0] = w0;  tk_w[t * 2 + 1] = w1;
    atomicAdd(&counts[e0], 1); atomicAdd(&counts[e1], 1);
  }
}

// ---------------- scan: offsets, tile maps (single thread; 8 experts, trivial) ----------
__global__ void scan_kernel(const int* __restrict__ counts, int* __restrict__ offsets,
                            int* __restrict__ cursors, int4* __restrict__ tilemap,
                            int4* __restrict__ tilemap64) {
  if (threadIdx.x != 0) return;
  int off = 0, nt = 0, nt2 = 0;
  for (int e = 0; e < NEXP; ++e) {
    offsets[e] = off; cursors[e] = 0;
    int c = counts[e];
    for (int tm = 0; tm * BM < c; ++tm)
      tilemap[nt++] = make_int4(e, off + tm * BM, min(BM, c - tm * BM), 0);
    for (int tm = 0; tm * 64 < c; ++tm)
      tilemap64[nt2++] = make_int4(e, off + tm * 64, min(64, c - tm * 64), 0);
    off += c;
  }
  offsets[NEXP] = off;
  for (; nt < MAXT; ++nt) tilemap[nt] = make_int4(-1, 0, 0, 0);
  for (; nt2 < MAXT64; ++nt2) tilemap64[nt2] = make_int4(-1, 0, 0, 0);
}

// ---------------- scatter: build per-expert sorted row lists ----------------------------
__global__ void scatter_kernel(const int* __restrict__ tk_id, const float* __restrict__ tk_w,
                               const int* __restrict__ offsets, int* __restrict__ cursors,
                               int* __restrict__ rowmap, float* __restrict__ roww) {
  int i = blockIdx.x * 256 + threadIdx.x;      // 0 .. RTOT-1
  int t = i >> 1;
  int e = tk_id[i]; float w = tk_w[i];
  int p = atomicAdd(&cursors[e], 1);
  rowmap[offsets[e] + p] = t; roww[offsets[e] + p] = w;
}

// ---------------- transpose-cast w1/w3 -> interleaved Bi[E][FFI][HID] (LDS-staged) ------
// w1 col c -> Bi row 32*(c>>4)+(c&15); w3 col c -> +16. Coalesced reads AND writes.
__global__ void transpose_cast_dual_kernel(const float* __restrict__ w1,
                                           const float* __restrict__ w3,
                                           u16* __restrict__ bi) {
  __shared__ __attribute__((aligned(16))) u16 tile[64][72];
  const int z = blockIdx.z, e = z >> 1, half = z & 1;
  const float* src = (half ? w3 : w1) + (size_t)e * HID * FFN;   // [HID][FFN]
  u16* dst = bi + (size_t)e * FFI * HID;
  const int c0 = blockIdx.x * 64, r0 = blockIdx.y * 64;
  const int t = threadIdx.x;
  const int rr = t >> 4, cc = (t & 15) * 4;
#pragma unroll
  for (int it = 0; it < 4; ++it) {
    int r = it * 16 + rr;
    float4 v = *(const float4*)(src + (size_t)(r0 + r) * FFN + c0 + cc);
    tile[cc + 0][r] = f2b(v.x);
    tile[cc + 1][r] = f2b(v.y);
    tile[cc + 2][r] = f2b(v.z);
    tile[cc + 3][r] = f2b(v.w);
  }
  __syncthreads();
  const int cl = t >> 2;            // local col 0..63
  const int och = (t & 3) * 16;
  const int orow = (c0 << 1) + ((cl >> 4) << 5) + (cl & 15) + (half << 4);
  u16* dp = dst + (size_t)orow * HID + r0 + och;
  *(bvec8*)(dp + 0) = *(const bvec8*)&tile[cl][och + 0];
  *(bvec8*)(dp + 8) = *(const bvec8*)&tile[cl][och + 8];
}

// ---------------- transpose-cast w2 [E][FFN][HID] -> w2t [E][HID][FFN] (LDS-staged) -----
__global__ void transpose_cast_w2_kernel(const float* __restrict__ w2, u16* __restrict__ w2t) {
  __shared__ __attribute__((aligned(16))) u16 tile[64][72];
  const int e = blockIdx.z;
  const float* src = w2 + (size_t)e * FFN * HID;   // [FFN][HID]
  u16* dst = w2t + (size_t)e * HID * FFN;          // [HID][FFN]
  const int c0 = blockIdx.x * 64, r0 = blockIdx.y * 64;
  const int t = threadIdx.x;
  const int rr = t >> 4, cc = (t & 15) * 4;
#pragma unroll
  for (int it = 0; it < 4; ++it) {
    int r = it * 16 + rr;
    float4 v = *(const float4*)(src + (size_t)(r0 + r) * HID + c0 + cc);
    tile[cc + 0][r] = f2b(v.x);
    tile[cc + 1][r] = f2b(v.y);
    tile[cc + 2][r] = f2b(v.z);
    tile[cc + 3][r] = f2b(v.w);
  }
  __syncthreads();
  const int cl = t >> 2;
  const int och = (t & 3) * 16;
  u16* dp = dst + (size_t)(c0 + cl) * FFN + r0 + och;
  *(bvec8*)(dp + 0) = *(const bvec8*)&tile[cl][och + 0];
  *(bvec8*)(dp + 8) = *(const bvec8*)&tile[cl][och + 8];
}

// ---------------- GEMM1: 128x128, BK=64, m97 2-barrier structure, interleaved Bi --------
// Staging: 8 x gload16/thread (4 rounds A + 4 rounds B of 32 rows each).
// LDS row = 64 bf16 = 8 x 16B chunks; swizzle phys_chunk = log_chunk ^ (row&7):
// applied on global source (staging) and on ds_read -> 2-way bank aliasing only (free).
__launch_bounds__(256, 3)
__global__ void gemm1_kernel(const u16* __restrict__ xb, const u16* __restrict__ bi,
                             const int* __restrict__ rowmap,
                             const int4* __restrict__ tilemap, u16* __restrict__ hbuf) {
  const int wg = xcd_swz(blockIdx.x, NT1 * MAXT);
  const int mt = wg % MAXT;          // M fastest within an XCD chunk -> B-panel L2 reuse
  const int nt = wg / MAXT;
  int4 ti = tilemap[mt];
  if (ti.x < 0) return;
  const int e = ti.x, rowbase = ti.y, mvalid = ti.z;
  const int n0 = nt * BN;

  __shared__ __attribute__((aligned(128))) u16 As[BM * BK];   // 16KB
  __shared__ __attribute__((aligned(128))) u16 Bs[BN * BK];   // 16KB

  const int tid = threadIdx.x;
  const int lane = tid & 63;
  const int wv = tid >> 6;

  // staging: round r covers rows r*32 + (tid>>3); chunk = tid&7 (16B units)
  const int srow = tid >> 3;                         // 0..31
  const int csrc = ((tid & 7) ^ (srow & 7)) * 8;     // pre-swizzled source chunk (elems)
  const u16* wb = bi + (size_t)e * FFI * HID;
  const u16* gA[4]; const u16* gB[4];
  u16* lA[4]; u16* lB[4];
#pragma unroll
  for (int r = 0; r < 4; ++r) {
    int row = r * 32 + srow;
    int tok = rowmap[min(rowbase + row, RTOT - 1)];
    gA[r] = xb + (size_t)tok * HID + csrc;
    gB[r] = wb + (size_t)(n0 + row) * HID + csrc;
    lA[r] = &As[(r * 32 + wv * 8) * BK];             // wave-uniform dests
    lB[r] = &Bs[(r * 32 + wv * 8) * BK];
  }

  const int wm = (tid >> 7) & 1, wn = (tid >> 6) & 1;   // 2x2 waves, 64x64 each
  const int l15 = lane & 15;
  const int kg = lane >> 4;                          // 0..3
  const int swz = l15 & 7;
  const int aBase = (wm * 64 + l15) * BK;
  const int bBase = (wn * 64 + l15) * BK;
  const int ch0 = ((0 + kg) ^ swz) * 8;              // ks=0 phys chunk (elems)
  const int ch1 = ((4 + kg) ^ swz) * 8;              // ks=1

  fvec4 acc[4][4] = {};

  for (int kt = 0; kt < HID / BK; ++kt) {            // 16 iters
#pragma unroll
    for (int r = 0; r < 4; ++r) { gload16(gA[r], lA[r]); gA[r] += BK; }
#pragma unroll
    for (int r = 0; r < 4; ++r) { gload16(gB[r], lB[r]); gB[r] += BK; }
    __syncthreads();
    bvec8 a0[4], a1[4];
#pragma unroll
    for (int mi = 0; mi < 4; ++mi) {
      a0[mi] = *(const bvec8*)&As[aBase + mi * 16 * BK + ch0];
      a1[mi] = *(const bvec8*)&As[aBase + mi * 16 * BK + ch1];
    }
#pragma unroll
    for (int ni = 0; ni < 4; ++ni) {
      bvec8 b0 = *(const bvec8*)&Bs[bBase + ni * 16 * BK + ch0];
#pragma unroll
      for (int mi = 0; mi < 4; ++mi)
        acc[mi][ni] = __builtin_amdgcn_mfma_f32_16x16x32_bf16(a0[mi], b0, acc[mi][ni], 0, 0, 0);
      bvec8 b1 = *(const bvec8*)&Bs[bBase + ni * 16 * BK + ch1];
#pragma unroll
      for (int mi = 0; mi < 4; ++mi)
        acc[mi][ni] = __builtin_amdgcn_mfma_f32_16x16x32_bf16(a1[mi], b1, acc[mi][ni], 0, 0, 0);
    }
    __syncthreads();
  }
  // epilogue: pair ni (even=g, odd=u): h = silu(g) * u, bf16
  const int rg4 = (lane >> 4) * 4;
#pragma unroll
  for (int mi = 0; mi < 4; ++mi) {
#pragma unroll
    for (int j = 0; j < 4; ++j) {
      int ml = wm * 64 + mi * 16 + rg4 + j;
      if (ml < mvalid) {
        size_t rowoff = (size_t)(rowbase + ml) * FFN + ((n0 + wn * 64) >> 1);
#pragma unroll
        for (int np = 0; np < 2; ++np) {
          float g = acc[mi][2 * np][j], u = acc[mi][2 * np + 1][j];
          float hv = (g / (1.f + expf(-g))) * u;
          hbuf[rowoff + np * 16 + l15] = f2b(hv);
        }
      }
    }
  }
}

// ---------------- GEMM2: 64x128 tiles, BK=64, 128 threads, 6 blocks/CU ------------------
// out[token] += weight * (h @ w2). ~1030 real blocks -> all co-resident, no tail.
__launch_bounds__(128, 3)
__global__ void gemm2_kernel(const u16* __restrict__ hbuf, const u16* __restrict__ w2t,
                             const int* __restrict__ rowmap, const float* __restrict__ roww,
                             const int4* __restrict__ tilemap64, float* __restrict__ out) {
  const int wg = xcd_swz(blockIdx.x, NT2 * MAXT64);
  const int mt = wg % MAXT64;
  const int nt = wg / MAXT64;
  int4 ti = tilemap64[mt];
  if (ti.x < 0) return;
  const int e = ti.x, rowbase = ti.y, mvalid = ti.z;
  const int n0 = nt * 128;

  __shared__ __attribute__((aligned(128))) u16 As[64 * BK];    // 8KB
  __shared__ __attribute__((aligned(128))) u16 Bs[128 * BK];   // 16KB

  const int tid = threadIdx.x;        // 0..127
  const int lane = tid & 63;
  const int wv = tid >> 6;            // 0..1

  // staging: rounds of 16 rows (128 threads x 16B = 2KB); A: 4 rounds, B: 8 rounds
  const int srow = tid >> 3;                         // 0..15
  const int csrc = ((tid & 7) ^ (srow & 7)) * 8;
  const u16* wb2 = w2t + (size_t)e * HID * FFN;
  const u16* gA[4]; const u16* gB[8];
  u16* lA[4]; u16* lB[8];
#pragma unroll
  for (int r = 0; r < 4; ++r) {
    int row = r * 16 + srow;
    gA[r] = hbuf + (size_t)min(rowbase + row, RTOT - 1) * FFN + csrc;
    lA[r] = &As[(r * 16 + wv * 8) * BK];
  }
#pragma unroll
  for (int r = 0; r < 8; ++r) {
    int row = r * 16 + srow;
    gB[r] = wb2 + (size_t)(n0 + row) * FFN + csrc;
    lB[r] = &Bs[(r * 16 + wv * 8) * BK];
  }

  const int wn = wv;                                 // wave covers cols wn*64..+63
  const int l15 = lane & 15;
  const int kg = lane >> 4;
  const int swz = l15 & 7;
  const int aBase = l15 * BK;
  const int bBase = (wn * 64 + l15) * BK;
  const int ch0 = ((0 + kg) ^ swz) * 8;
  const int ch1 = ((4 + kg) ^ swz) * 8;

  fvec4 acc[4][4] = {};

  for (int kt = 0; kt < FFN / BK; ++kt) {            // 56 iters
#pragma unroll
    for (int r = 0; r < 4; ++r) { gload16(gA[r], lA[r]); gA[r] += BK; }
#pragma unroll
    for (int r = 0; r < 8; ++r) { gload16(gB[r], lB[r]); gB[r] += BK; }
    __syncthreads();
    bvec8 a0[4], a1[4];
#pragma unroll
    for (int mi = 0; mi < 4; ++mi) {
      a0[mi] = *(const bvec8*)&As[aBase + mi * 16 * BK + ch0];
      a1[mi] = *(const bvec8*)&As[aBase + mi * 16 * BK + ch1];
    }
#pragma unroll
    for (int ni = 0; ni < 4; ++ni) {
      bvec8 b0 = *(const bvec8*)&Bs[bBase + ni * 16 * BK + ch0];
#pragma unroll
      for (int mi = 0; mi < 4; ++mi)
        acc[mi][ni] = __builtin_amdgcn_mfma_f32_16x16x32_bf16(a0[mi], b0, acc[mi][ni], 0, 0, 0);
      bvec8 b1 = *(const bvec8*)&Bs[bBase + ni * 16 * BK + ch1];
#pragma unroll
      for (int mi = 0; mi < 4; ++mi)
        acc[mi][ni] = __builtin_amdgcn_mfma_f32_16x16x32_bf16(a1[mi], b1, acc[mi][ni], 0, 0, 0);
    }
    __syncthreads();
  }
  // epilogue: weighted atomic combine into out[token]
  const int rg4 = (lane >> 4) * 4;
#pragma unroll
  for (int mi = 0; mi < 4; ++mi) {
#pragma unroll
    for (int j = 0; j < 4; ++j) {
      int ml = mi * 16 + rg4 + j;
      if (ml < mvalid) {
        int r = rowbase + ml;
        int tk = rowmap[r];
        float wgt = roww[r];
        float* op = out + (size_t)tk * HID + n0 + wn * 64;
#pragma unroll
        for (int ni = 0; ni < 4; ++ni)
          atomicAdd(&op[ni * 16 + l15], acc[mi][ni][j] * wgt);
      }
    }
  }
}

// ---------------- launcher --------------------------------------------------------------
extern "C" void kernel_launch(void* const* d_in, const int* in_sizes, int n_in,
                              void* d_out, int out_size, void* d_ws, size_t ws_size,
                              hipStream_t stream) {
  (void)in_sizes; (void)n_in; (void)out_size;
  const float* x  = (const float*)d_in[0];
  const float* gw = (const float*)d_in[1];
  const float* w1 = (const float*)d_in[2];
  const float* w2 = (const float*)d_in[3];   // NOTE: dict order is w1, w2, w3
  const float* w3 = (const float*)d_in[4];
  float* out = (float*)d_out;
  float* logits = out + (size_t)T_TOK * HID;

  size_t off = 0;
  auto take = [&](size_t b) { size_t o = off; off += (b + 255) & ~(size_t)255; return o; };
  size_t o_xb   = take((size_t)T_TOK * HID * 2);           // x bf16
  size_t o_wt   = take((size_t)NEXP * FFI * HID * 2);      // Bi (interleaved w1/w3); w2t reuses
  size_t o_hb   = take((size_t)RTOT * FFN * 2);            // h bf16
  size_t o_rmap = take((size_t)RTOT * 4);
  size_t o_rw   = take((size_t)RTOT * 4);
  size_t o_tid  = take((size_t)RTOT * 4);
  size_t o_tw   = take((size_t)RTOT * 4);
  size_t o_cnt  = take(4 * NEXP);
  size_t o_ofs  = take(4 * (NEXP + 1));
  size_t o_cur  = take(4 * NEXP);
  size_t o_tmap = take(MAXT * 16);
  size_t o_tmap64 = take(MAXT64 * 16);
  size_t total = off;

  hipMemsetAsync(d_out, 0, (size_t)T_TOK * HID * sizeof(float), stream);
  if (ws_size < total) {
    router_kernel<<<T_TOK / 4, 256, 0, stream>>>(x, gw, logits, nullptr, nullptr, nullptr,
                                                 nullptr, 0);
    return;
  }

  char* w = (char*)d_ws;
  u16* xb   = (u16*)(w + o_xb);
  u16* bi   = (u16*)(w + o_wt);
  u16* w2t  = bi;                                   // reused after gemm1 completes
  u16* hb   = (u16*)(w + o_hb);
  int*   rmap = (int*)(w + o_rmap);
  float* rw   = (float*)(w + o_rw);
  int*   tkid = (int*)(w + o_tid);
  float* tkw  = (float*)(w + o_tw);
  int*   cnt  = (int*)(w + o_cnt);
  int*   ofs  = (int*)(w + o_ofs);
  int*   cur  = (int*)(w + o_cur);
  int4*  tmap = (int4*)(w + o_tmap);
  int4*  tmap64 = (int4*)(w + o_tmap64);

  hipMemsetAsync(cnt, 0, 4 * NEXP, stream);
  router_kernel<<<T_TOK / 4, 256, 0, stream>>>(x, gw, logits, tkid, tkw, cnt, xb, 1);
  scan_kernel<<<1, 64, 0, stream>>>(cnt, ofs, cur, tmap, tmap64);
  scatter_kernel<<<RTOT / 256, 256, 0, stream>>>(tkid, tkw, ofs, cur, rmap, rw);
  transpose_cast_dual_kernel<<<dim3(FFN / 64, HID / 64, 2 * NEXP), 256, 0, stream>>>(w1, w3, bi);
  gemm1_kernel<<<NT1 * MAXT, 256, 0, stream>>>(xb, bi, rmap, tmap, hb);
  transpose_cast_w2_kernel<<<dim3(HID / 64, FFN / 64, NEXP), 256, 0, stream>>>(w2, w2t);
  gemm2_kernel<<<NT2 * MAXT64, 128, 0, stream>>>(hb, w2t, rmap, rw, tmap64, out);
}

// Round 6
// 507.151 us; speedup vs baseline: 1.1064x; 1.0140x over previous
//
#include <hip/hip_runtime.h>
#include <hip/hip_bf16.h>
#include <cstdint>
#include <cstddef>

#define T_TOK 4096
#define HID   1024
#define FFN   3584
#define FFI   (2 * FFN)     // interleaved g/u columns: 7168
#define NEXP  8
#define RTOT  (T_TOK * 2)   // total (token, slot) rows = T * top_k
#define MAXT  72            // max 128-row M-tiles: floor(8192/128)+7=71, +1 slack
#define BM 128
#define BN 128
#define BK 64               // K-tile (halves barrier count vs 32)
#define NT1 (FFI / BN)      // 56 N-tiles for gemm1 (interleaved)
#define NT2 (HID / BN)      // 8 N-tiles for gemm2

typedef __attribute__((ext_vector_type(8))) short bvec8;   // 8 x bf16 (4 VGPR) MFMA operand
typedef __attribute__((ext_vector_type(4))) short bvec4;
typedef __attribute__((ext_vector_type(4))) float fvec4;   // MFMA accumulator
typedef unsigned short u16;

__device__ __forceinline__ u16 f2b(float f) {
  __bf16 b = (__bf16)f;                 // RNE convert
  return __builtin_bit_cast(u16, b);
}

// async global->LDS, 16B per lane. LDS dest must be wave-uniform base (HW adds lane*16).
__device__ __forceinline__ void gload16(const u16* g, u16* l) {
  __builtin_amdgcn_global_load_lds((const __attribute__((address_space(1))) void*)g,
                                   (__attribute__((address_space(3))) void*)l, 16, 0, 0);
}

// bijective XCD swizzle (m204): contiguous chunk of work per XCD
__device__ __forceinline__ int xcd_swz(int bid, int nwg) {
  int q = nwg >> 3, r = nwg & 7;
  int xcd = bid & 7, sub = bid >> 3;
  return (xcd < r ? xcd * (q + 1) : r * (q + 1) + (xcd - r) * q) + sub;
}

// ---------------- router: logits (fp32), top-2, combine weights, counts, + x->bf16 ------
__global__ void router_kernel(const float* __restrict__ x, const float* __restrict__ gw,
                              float* __restrict__ logits, int* __restrict__ tk_id,
                              float* __restrict__ tk_w, int* __restrict__ counts,
                              u16* __restrict__ xb, int full) {
  const int lane = threadIdx.x & 63;
  const int wid  = threadIdx.x >> 6;
  const int t = blockIdx.x * 4 + wid;          // one token per wave
  const float4* xr = (const float4*)(x + (size_t)t * HID);
  float acc[NEXP] = {0.f, 0.f, 0.f, 0.f, 0.f, 0.f, 0.f, 0.f};
#pragma unroll
  for (int it = 0; it < 4; ++it) {
    int k4 = it * 64 + lane;                   // float4 index, covers H/4 = 256
    float4 xv = xr[k4];
    if (xb) {                                  // fused bf16 cast of x
      bvec4 o;
      o[0] = (short)f2b(xv.x); o[1] = (short)f2b(xv.y);
      o[2] = (short)f2b(xv.z); o[3] = (short)f2b(xv.w);
      *(bvec4*)(xb + (size_t)t * HID + k4 * 4) = o;
    }
    const float* gp = gw + (size_t)k4 * 4 * NEXP;
    float xs[4] = {xv.x, xv.y, xv.z, xv.w};
#pragma unroll
    for (int kk = 0; kk < 4; ++kk) {
      float4 ga = ((const float4*)(gp + kk * NEXP))[0];
      float4 gb = ((const float4*)(gp + kk * NEXP))[1];
      acc[0] += xs[kk] * ga.x; acc[1] += xs[kk] * ga.y;
      acc[2] += xs[kk] * ga.z; acc[3] += xs[kk] * ga.w;
      acc[4] += xs[kk] * gb.x; acc[5] += xs[kk] * gb.y;
      acc[6] += xs[kk] * gb.z; acc[7] += xs[kk] * gb.w;
    }
  }
#pragma unroll
  for (int off = 32; off > 0; off >>= 1) {
#pragma unroll
    for (int e = 0; e < NEXP; ++e) acc[e] += __shfl_xor(acc[e], off, 64);
  }
  if (lane < NEXP) logits[(size_t)t * NEXP + lane] = acc[lane];
  if (full && lane == 0) {
    int e0 = 0; float l0 = acc[0];
#pragma unroll
    for (int e = 1; e < NEXP; ++e) if (acc[e] > l0) { l0 = acc[e]; e0 = e; }
    int e1 = -1; float l1 = -3.4e38f;
#pragma unroll
    for (int e = 0; e < NEXP; ++e) if (e != e0 && acc[e] > l1) { l1 = acc[e]; e1 = e; }
    float w0 = 1.f / (1.f + expf(l1 - l0));
    float w1 = 1.f - w0;
    tk_id[t * 2 + 0] = e0; tk_id[t * 2 + 1] = e1;
    tk_w[t * 2 + 0] = w0;  tk_w[t * 2 + 1] = w1;
    atomicAdd(&counts[e0], 1); atomicAdd(&counts[e1], 1);
  }
}

// ---------------- scan: offsets, tile map (single thread; 8 experts, trivial) -----------
__global__ void scan_kernel(const int* __restrict__ counts, int* __restrict__ offsets,
                            int* __restrict__ cursors, int4* __restrict__ tilemap) {
  if (threadIdx.x != 0) return;
  int off = 0, nt = 0;
  for (int e = 0; e < NEXP; ++e) {
    offsets[e] = off; cursors[e] = 0;
    int c = counts[e];
    for (int tm = 0; tm * BM < c; ++tm)
      tilemap[nt++] = make_int4(e, off + tm * BM, min(BM, c - tm * BM), 0);
    off += c;
  }
  offsets[NEXP] = off;
  for (; nt < MAXT; ++nt) tilemap[nt] = make_int4(-1, 0, 0, 0);
}

// ---------------- scatter: build per-expert sorted row lists ----------------------------
__global__ void scatter_kernel(const int* __restrict__ tk_id, const float* __restrict__ tk_w,
                               const int* __restrict__ offsets, int* __restrict__ cursors,
                               int* __restrict__ rowmap, float* __restrict__ roww) {
  int i = blockIdx.x * 256 + threadIdx.x;      // 0 .. RTOT-1
  int t = i >> 1;
  int e = tk_id[i]; float w = tk_w[i];
  int p = atomicAdd(&cursors[e], 1);
  rowmap[offsets[e] + p] = t; roww[offsets[e] + p] = w;
}

// ---------------- transpose-cast w1/w3 -> interleaved Bi[E][FFI][HID] (LDS-staged) ------
// w1 col c -> Bi row 32*(c>>4)+(c&15); w3 col c -> +16. Coalesced reads AND writes.
__global__ void transpose_cast_dual_kernel(const float* __restrict__ w1,
                                           const float* __restrict__ w3,
                                           u16* __restrict__ bi) {
  __shared__ __attribute__((aligned(16))) u16 tile[64][72];
  const int z = blockIdx.z, e = z >> 1, half = z & 1;
  const float* src = (half ? w3 : w1) + (size_t)e * HID * FFN;   // [HID][FFN]
  u16* dst = bi + (size_t)e * FFI * HID;
  const int c0 = blockIdx.x * 64, r0 = blockIdx.y * 64;
  const int t = threadIdx.x;
  const int rr = t >> 4, cc = (t & 15) * 4;
#pragma unroll
  for (int it = 0; it < 4; ++it) {
    int r = it * 16 + rr;
    float4 v = *(const float4*)(src + (size_t)(r0 + r) * FFN + c0 + cc);
    tile[cc + 0][r] = f2b(v.x);
    tile[cc + 1][r] = f2b(v.y);
    tile[cc + 2][r] = f2b(v.z);
    tile[cc + 3][r] = f2b(v.w);
  }
  __syncthreads();
  const int cl = t >> 2;            // local col 0..63
  const int och = (t & 3) * 16;
  const int orow = (c0 << 1) + ((cl >> 4) << 5) + (cl & 15) + (half << 4);
  u16* dp = dst + (size_t)orow * HID + r0 + och;
  *(bvec8*)(dp + 0) = *(const bvec8*)&tile[cl][och + 0];
  *(bvec8*)(dp + 8) = *(const bvec8*)&tile[cl][och + 8];
}

// ---------------- transpose-cast w2 [E][FFN][HID] -> w2t [E][HID][FFN] (LDS-staged) -----
__global__ void transpose_cast_w2_kernel(const float* __restrict__ w2, u16* __restrict__ w2t) {
  __shared__ __attribute__((aligned(16))) u16 tile[64][72];
  const int e = blockIdx.z;
  const float* src = w2 + (size_t)e * FFN * HID;   // [FFN][HID]
  u16* dst = w2t + (size_t)e * HID * FFN;          // [HID][FFN]
  const int c0 = blockIdx.x * 64, r0 = blockIdx.y * 64;
  const int t = threadIdx.x;
  const int rr = t >> 4, cc = (t & 15) * 4;
#pragma unroll
  for (int it = 0; it < 4; ++it) {
    int r = it * 16 + rr;
    float4 v = *(const float4*)(src + (size_t)(r0 + r) * HID + c0 + cc);
    tile[cc + 0][r] = f2b(v.x);
    tile[cc + 1][r] = f2b(v.y);
    tile[cc + 2][r] = f2b(v.z);
    tile[cc + 3][r] = f2b(v.w);
  }
  __syncthreads();
  const int cl = t >> 2;
  const int och = (t & 3) * 16;
  u16* dp = dst + (size_t)(c0 + cl) * FFN + r0 + och;
  *(bvec8*)(dp + 0) = *(const bvec8*)&tile[cl][och + 0];
  *(bvec8*)(dp + 8) = *(const bvec8*)&tile[cl][och + 8];
}

// ---------------- GEMM1: 128x128, BK=64, m97 2-barrier structure, interleaved Bi --------
// Staging: 8 x gload16/thread (4 rounds A + 4 rounds B of 32 rows each).
// LDS row = 64 bf16 = 8 x 16B chunks; swizzle phys_chunk = log_chunk ^ (row&7):
// applied on global source (staging) and on ds_read -> 2-way bank aliasing only (free).
__launch_bounds__(256, 3)
__global__ void gemm1_kernel(const u16* __restrict__ xb, const u16* __restrict__ bi,
                             const int* __restrict__ rowmap,
                             const int4* __restrict__ tilemap, u16* __restrict__ hbuf) {
  const int wg = xcd_swz(blockIdx.x, NT1 * MAXT);
  const int mt = wg % MAXT;          // M fastest within an XCD chunk -> B-panel L2 reuse
  const int nt = wg / MAXT;
  int4 ti = tilemap[mt];
  if (ti.x < 0) return;
  const int e = ti.x, rowbase = ti.y, mvalid = ti.z;
  const int n0 = nt * BN;

  __shared__ __attribute__((aligned(128))) u16 As[BM * BK];   // 16KB
  __shared__ __attribute__((aligned(128))) u16 Bs[BN * BK];   // 16KB

  const int tid = threadIdx.x;
  const int lane = tid & 63;
  const int wv = tid >> 6;

  // staging: round r covers rows r*32 + (tid>>3); chunk = tid&7 (16B units)
  const int srow = tid >> 3;                         // 0..31
  const int csrc = ((tid & 7) ^ (srow & 7)) * 8;     // pre-swizzled source chunk (elems)
  const u16* wb = bi + (size_t)e * FFI * HID;
  const u16* gA[4]; const u16* gB[4];
  u16* lA[4]; u16* lB[4];
#pragma unroll
  for (int r = 0; r < 4; ++r) {
    int row = r * 32 + srow;
    int tok = rowmap[min(rowbase + row, RTOT - 1)];
    gA[r] = xb + (size_t)tok * HID + csrc;
    gB[r] = wb + (size_t)(n0 + row) * HID + csrc;
    lA[r] = &As[(r * 32 + wv * 8) * BK];             // wave-uniform dests
    lB[r] = &Bs[(r * 32 + wv * 8) * BK];
  }

  const int wm = (tid >> 7) & 1, wn = (tid >> 6) & 1;   // 2x2 waves, 64x64 each
  const int l15 = lane & 15;
  const int kg = lane >> 4;                          // 0..3
  const int swz = l15 & 7;
  const int aBase = (wm * 64 + l15) * BK;
  const int bBase = (wn * 64 + l15) * BK;
  const int ch0 = ((0 + kg) ^ swz) * 8;              // ks=0 phys chunk (elems)
  const int ch1 = ((4 + kg) ^ swz) * 8;              // ks=1

  fvec4 acc[4][4] = {};

  for (int kt = 0; kt < HID / BK; ++kt) {            // 16 iters
#pragma unroll
    for (int r = 0; r < 4; ++r) { gload16(gA[r], lA[r]); gA[r] += BK; }
#pragma unroll
    for (int r = 0; r < 4; ++r) { gload16(gB[r], lB[r]); gB[r] += BK; }
    __syncthreads();
    bvec8 a0[4], a1[4];
#pragma unroll
    for (int mi = 0; mi < 4; ++mi) {
      a0[mi] = *(const bvec8*)&As[aBase + mi * 16 * BK + ch0];
      a1[mi] = *(const bvec8*)&As[aBase + mi * 16 * BK + ch1];
    }
#pragma unroll
    for (int ni = 0; ni < 4; ++ni) {
      bvec8 b0 = *(const bvec8*)&Bs[bBase + ni * 16 * BK + ch0];
#pragma unroll
      for (int mi = 0; mi < 4; ++mi)
        acc[mi][ni] = __builtin_amdgcn_mfma_f32_16x16x32_bf16(a0[mi], b0, acc[mi][ni], 0, 0, 0);
      bvec8 b1 = *(const bvec8*)&Bs[bBase + ni * 16 * BK + ch1];
#pragma unroll
      for (int mi = 0; mi < 4; ++mi)
        acc[mi][ni] = __builtin_amdgcn_mfma_f32_16x16x32_bf16(a1[mi], b1, acc[mi][ni], 0, 0, 0);
    }
    __syncthreads();
  }
  // epilogue: pair ni (even=g, odd=u): h = silu(g) * u, bf16
  const int rg4 = (lane >> 4) * 4;
#pragma unroll
  for (int mi = 0; mi < 4; ++mi) {
#pragma unroll
    for (int j = 0; j < 4; ++j) {
      int ml = wm * 64 + mi * 16 + rg4 + j;
      if (ml < mvalid) {
        size_t rowoff = (size_t)(rowbase + ml) * FFN + ((n0 + wn * 64) >> 1);
#pragma unroll
        for (int np = 0; np < 2; ++np) {
          float g = acc[mi][2 * np][j], u = acc[mi][2 * np + 1][j];
          float hv = (g / (1.f + expf(-g))) * u;
          hbuf[rowoff + np * 16 + l15] = f2b(hv);
        }
      }
    }
  }
}

// ---------------- GEMM2: 128x128, BK=64, same proven structure; weighted atomic combine -
__launch_bounds__(256, 3)
__global__ void gemm2_kernel(const u16* __restrict__ hbuf, const u16* __restrict__ w2t,
                             const int* __restrict__ rowmap, const float* __restrict__ roww,
                             const int4* __restrict__ tilemap, float* __restrict__ out) {
  const int wg = xcd_swz(blockIdx.x, NT2 * MAXT);
  const int mt = wg % MAXT;          // M fastest -> B-panel (896KB) stays in XCD L2
  const int nt = wg / MAXT;
  int4 ti = tilemap[mt];
  if (ti.x < 0) return;
  const int e = ti.x, rowbase = ti.y, mvalid = ti.z;
  const int n0 = nt * BN;

  __shared__ __attribute__((aligned(128))) u16 As[BM * BK];   // 16KB
  __shared__ __attribute__((aligned(128))) u16 Bs[BN * BK];   // 16KB

  const int tid = threadIdx.x;
  const int lane = tid & 63;
  const int wv = tid >> 6;

  const int srow = tid >> 3;                         // 0..31
  const int csrc = ((tid & 7) ^ (srow & 7)) * 8;
  const u16* wb2 = w2t + (size_t)e * HID * FFN;
  const u16* gA[4]; const u16* gB[4];
  u16* lA[4]; u16* lB[4];
#pragma unroll
  for (int r = 0; r < 4; ++r) {
    int row = r * 32 + srow;
    gA[r] = hbuf + (size_t)min(rowbase + row, RTOT - 1) * FFN + csrc;
    gB[r] = wb2 + (size_t)(n0 + row) * FFN + csrc;
    lA[r] = &As[(r * 32 + wv * 8) * BK];
    lB[r] = &Bs[(r * 32 + wv * 8) * BK];
  }

  const int wm = (tid >> 7) & 1, wn = (tid >> 6) & 1;
  const int l15 = lane & 15;
  const int kg = lane >> 4;
  const int swz = l15 & 7;
  const int aBase = (wm * 64 + l15) * BK;
  const int bBase = (wn * 64 + l15) * BK;
  const int ch0 = ((0 + kg) ^ swz) * 8;
  const int ch1 = ((4 + kg) ^ swz) * 8;

  fvec4 acc[4][4] = {};

  for (int kt = 0; kt < FFN / BK; ++kt) {            // 56 iters
#pragma unroll
    for (int r = 0; r < 4; ++r) { gload16(gA[r], lA[r]); gA[r] += BK; }
#pragma unroll
    for (int r = 0; r < 4; ++r) { gload16(gB[r], lB[r]); gB[r] += BK; }
    __syncthreads();
    bvec8 a0[4], a1[4];
#pragma unroll
    for (int mi = 0; mi < 4; ++mi) {
      a0[mi] = *(const bvec8*)&As[aBase + mi * 16 * BK + ch0];
      a1[mi] = *(const bvec8*)&As[aBase + mi * 16 * BK + ch1];
    }
#pragma unroll
    for (int ni = 0; ni < 4; ++ni) {
      bvec8 b0 = *(const bvec8*)&Bs[bBase + ni * 16 * BK + ch0];
#pragma unroll
      for (int mi = 0; mi < 4; ++mi)
        acc[mi][ni] = __builtin_amdgcn_mfma_f32_16x16x32_bf16(a0[mi], b0, acc[mi][ni], 0, 0, 0);
      bvec8 b1 = *(const bvec8*)&Bs[bBase + ni * 16 * BK + ch1];
#pragma unroll
      for (int mi = 0; mi < 4; ++mi)
        acc[mi][ni] = __builtin_amdgcn_mfma_f32_16x16x32_bf16(a1[mi], b1, acc[mi][ni], 0, 0, 0);
    }
    __syncthreads();
  }
  // epilogue: weighted atomic combine into out[token]
  const int rg4 = (lane >> 4) * 4;
#pragma unroll
  for (int mi = 0; mi < 4; ++mi) {
#pragma unroll
    for (int j = 0; j < 4; ++j) {
      int ml = wm * 64 + mi * 16 + rg4 + j;
      if (ml < mvalid) {
        int r = rowbase + ml;
        int tk = rowmap[r];
        float wgt = roww[r];
        float* op = out + (size_t)tk * HID + n0 + wn * 64;
#pragma unroll
        for (int ni = 0; ni < 4; ++ni)
          atomicAdd(&op[ni * 16 + l15], acc[mi][ni][j] * wgt);
      }
    }
  }
}

// ---------------- launcher --------------------------------------------------------------
extern "C" void kernel_launch(void* const* d_in, const int* in_sizes, int n_in,
                              void* d_out, int out_size, void* d_ws, size_t ws_size,
                              hipStream_t stream) {
  (void)in_sizes; (void)n_in; (void)out_size;
  const float* x  = (const float*)d_in[0];
  const float* gw = (const float*)d_in[1];
  const float* w1 = (const float*)d_in[2];
  const float* w2 = (const float*)d_in[3];   // NOTE: dict order is w1, w2, w3
  const float* w3 = (const float*)d_in[4];
  float* out = (float*)d_out;
  float* logits = out + (size_t)T_TOK * HID;

  size_t off = 0;
  auto take = [&](size_t b) { size_t o = off; off += (b + 255) & ~(size_t)255; return o; };
  size_t o_xb   = take((size_t)T_TOK * HID * 2);           // x bf16
  size_t o_wt   = take((size_t)NEXP * FFI * HID * 2);      // Bi (interleaved w1/w3); w2t reuses
  size_t o_hb   = take((size_t)RTOT * FFN * 2);            // h bf16
  size_t o_rmap = take((size_t)RTOT * 4);
  size_t o_rw   = take((size_t)RTOT * 4);
  size_t o_tid  = take((size_t)RTOT * 4);
  size_t o_tw   = take((size_t)RTOT * 4);
  size_t o_cnt  = take(4 * NEXP);
  size_t o_ofs  = take(4 * (NEXP + 1));
  size_t o_cur  = take(4 * NEXP);
  size_t o_tmap = take(MAXT * 16);
  size_t total = off;

  hipMemsetAsync(d_out, 0, (size_t)T_TOK * HID * sizeof(float), stream);
  if (ws_size < total) {
    router_kernel<<<T_TOK / 4, 256, 0, stream>>>(x, gw, logits, nullptr, nullptr, nullptr,
                                                 nullptr, 0);
    return;
  }

  char* w = (char*)d_ws;
  u16* xb   = (u16*)(w + o_xb);
  u16* bi   = (u16*)(w + o_wt);
  u16* w2t  = bi;                                   // reused after gemm1 completes
  u16* hb   = (u16*)(w + o_hb);
  int*   rmap = (int*)(w + o_rmap);
  float* rw   = (float*)(w + o_rw);
  int*   tkid = (int*)(w + o_tid);
  float* tkw  = (float*)(w + o_tw);
  int*   cnt  = (int*)(w + o_cnt);
  int*   ofs  = (int*)(w + o_ofs);
  int*   cur  = (int*)(w + o_cur);
  int4*  tmap = (int4*)(w + o_tmap);

  hipMemsetAsync(cnt, 0, 4 * NEXP, stream);
  router_kernel<<<T_TOK / 4, 256, 0, stream>>>(x, gw, logits, tkid, tkw, cnt, xb, 1);
  scan_kernel<<<1, 64, 0, stream>>>(cnt, ofs, cur, tmap);
  scatter_kernel<<<RTOT / 256, 256, 0, stream>>>(tkid, tkw, ofs, cur, rmap, rw);
  transpose_cast_dual_kernel<<<dim3(FFN / 64, HID / 64, 2 * NEXP), 256, 0, stream>>>(w1, w3, bi);
  gemm1_kernel<<<NT1 * MAXT, 256, 0, stream>>>(xb, bi, rmap, tmap, hb);
  transpose_cast_w2_kernel<<<dim3(HID / 64, FFN / 64, NEXP), 256, 0, stream>>>(w2, w2t);
  gemm2_kernel<<<NT2 * MAXT, 256, 0, stream>>>(hb, w2t, rmap, rw, tmap, out);
}